// Round 1
// 206.474 us; speedup vs baseline: 1.1423x; 1.1423x over previous
//
#include <hip/hip_runtime.h>

#define IMW 1024
#define IMH 1024
#define NB  8
#define HALF 25
#define STRIP 32
#define NCELL 64

#define W_R ((double)0.2989f)
#define W_G ((double)0.5870f)
#define W_B ((double)0.1140f)
#define INV_AREA (1.0 / 2601.0)

__device__ __forceinline__ int refl(int i, int n) {
    if (i < 0) i = -i;
    if (i >= n) i = 2 * n - 2 - i;
    return i;
}

// 51-window sum at pixel p from inclusive row cumsum C[0..IMW-1], reflect pad.
__device__ __forceinline__ double wsum(const double* __restrict__ C, int p) {
    int a = p + HALF; if (a > IMW - 1) a = IMW - 1;
    int b = p - HALF - 1;
    double s = C[a] - (b >= 0 ? C[b] : 0.0);
    if (p <= HALF - 1)      s += C[HALF - p] - C[0];                        // i<0 mirrored
    if (p >= IMW - HALF)    s += C[IMW - 2] - C[2*IMW - 2 - HALF - 1 - p];  // i>=IMW mirrored
    return s;
}

// init 64 min-cells (all-ones) and 64 max-cells (zero); gray>=0 so bit-order == double order
__global__ void k0_init(unsigned long long* cells) {
    cells[threadIdx.x] = ~0ULL;          // min cells
    cells[NCELL + threadIdx.x] = 0ULL;   // max cells
}

// One block per image row. Cumsum of gray/gray^2 via register prefix + wave
// shuffle scan, 2-read window sums -> interleaved float2{h1,h2} (f32 store is
// safe: |h|<=51, round err ~1.5e-6; /2601 after vertical sum -> ~3e-8 on m).
// Also stages gray as f32 so k2 doesn't re-read 100 MB of RGB.
// Min/max via hierarchical atomics over 64 cells (~128 ops/cell, parallel).
__global__ __launch_bounds__(256) void k1_rowpass(const float* __restrict__ in,
                                                  float2* __restrict__ hp,
                                                  float* __restrict__ gray,
                                                  unsigned long long* __restrict__ cells) {
    __shared__ double cs1[IMW];
    __shared__ double cs2[IMW];
    __shared__ double wt1[4], wt2[4], bmin[4], bmax[4];
    const int row = blockIdx.x;                 // 0 .. NB*IMH-1
    const long long base = (long long)row * IMW;
    const int t = threadIdx.x;
    const int lane = t & 63, w = t >> 6;

    // 4 consecutive pixels per thread = 12 floats = 3x float4 (48B, 16B-aligned)
    const float4* p4 = (const float4*)(in + base * 3);
    float4 f0 = p4[3*t], f1 = p4[3*t+1], f2 = p4[3*t+2];
    double g0 = (double)f0.x*W_R + (double)f0.y*W_G + (double)f0.z*W_B;
    double g1 = (double)f0.w*W_R + (double)f1.x*W_G + (double)f1.y*W_B;
    double g2 = (double)f1.z*W_R + (double)f1.w*W_G + (double)f2.x*W_B;
    double g3 = (double)f2.y*W_R + (double)f2.z*W_G + (double)f2.w*W_B;

    // stage gray (f32) for k2: 16B coalesced store
    ((float4*)(gray + base))[t] = make_float4((float)g0, (float)g1, (float)g2, (float)g3);

    double l1_0 = g0, l1_1 = l1_0 + g1, l1_2 = l1_1 + g2, l1_3 = l1_2 + g3;
    double q0 = g0*g0, q1 = g1*g1, q2 = g2*g2, q3 = g3*g3;
    double l2_0 = q0, l2_1 = l2_0 + q1, l2_2 = l2_1 + q2, l2_3 = l2_2 + q3;

    // block min/max
    double lmin = fmin(fmin(g0, g1), fmin(g2, g3));
    double lmax = fmax(fmax(g0, g1), fmax(g2, g3));
    for (int off = 32; off; off >>= 1) {
        lmin = fmin(lmin, __shfl_down(lmin, off));
        lmax = fmax(lmax, __shfl_down(lmax, off));
    }
    if (lane == 0) { bmin[w] = lmin; bmax[w] = lmax; }

    // wave-level inclusive scan of per-thread totals
    double v1 = l1_3, v2 = l2_3;
    for (int off = 1; off < 64; off <<= 1) {
        double u1 = __shfl_up(v1, off);
        double u2 = __shfl_up(v2, off);
        if (lane >= off) { v1 += u1; v2 += u2; }
    }
    if (lane == 63) { wt1[w] = v1; wt2[w] = v2; }
    __syncthreads();
    double e1 = v1 - l1_3, e2 = v2 - l2_3;   // exclusive prefix within wave
    for (int j = 0; j < w; j++) { e1 += wt1[j]; e2 += wt2[j]; }

    // write inclusive cumsum, 16B stores
    double2* c1 = (double2*)&cs1[4*t];
    double2* c2 = (double2*)&cs2[4*t];
    c1[0] = make_double2(e1 + l1_0, e1 + l1_1);
    c1[1] = make_double2(e1 + l1_2, e1 + l1_3);
    c2[0] = make_double2(e2 + l2_0, e2 + l2_1);
    c2[1] = make_double2(e2 + l2_2, e2 + l2_3);

    if (t == 0) {
        double m0 = fmin(fmin(bmin[0], bmin[1]), fmin(bmin[2], bmin[3]));
        double m1 = fmax(fmax(bmax[0], bmax[1]), fmax(bmax[2], bmax[3]));
        int cell = row & (NCELL - 1);   // adjacent rows -> different cells
        atomicMin(&cells[cell], (unsigned long long)__double_as_longlong(m0));
        atomicMax(&cells[NCELL + cell], (unsigned long long)__double_as_longlong(m1));
    }
    __syncthreads();

    // interleaved {h1,h2} -> 8B/lane coalesced stores (f32 rounding only at store)
    for (int k = 0; k < 4; k++) {
        int p = t + 256 * k;
        hp[base + p] = make_float2((float)wsum(cs1, p), (float)wsum(cs2, p));
    }
}

// Column pass: 1 column/thread, vertical running 51-window over interleaved hp.
// STRIP=32 -> 1024 blocks = 4 blocks/CU = 16 waves/CU (was 512 blocks / 20%
// occupancy, which left the streaming loop latency-bound at 3.8 TB/s).
// Strip-init re-reads ((51+2*32)/32 = 3.6 hp-rows/output-row) hit L2/L3: hp is
// 67 MB, fully LLC-resident.
// XCD-swizzled linear grid: batch = id&7 -> one image per XCD; consecutive ids
// walk y-strips so overlapping 51-row windows share L2.
// Sqrt/div-free Sauvola compare: g > m(1+0.2(s/r-1)) <=> A>0 && A^2 r^2 > 0.04 m^2 var.
__global__ __launch_bounds__(256) void k2_colpass(const float* __restrict__ gray,
                                                  const float2* __restrict__ hp,
                                                  const unsigned long long* __restrict__ cells,
                                                  float* __restrict__ out) {
    __shared__ double sr[2];
    const int t = threadIdx.x;
    if (t < 64) {
        unsigned long long mn = cells[t];
        unsigned long long mx = cells[NCELL + t];
        for (int off = 32; off; off >>= 1) {
            unsigned long long a = __shfl_down(mn, off);
            unsigned long long b = __shfl_down(mx, off);
            mn = (a < mn) ? a : mn;
            mx = (b > mx) ? b : mx;
        }
        if (t == 0) {
            sr[0] = __longlong_as_double((long long)mn);
            sr[1] = __longlong_as_double((long long)mx);
        }
    }
    __syncthreads();
    const double r  = 0.5 * (sr[1] - sr[0]);
    const double r2 = r * r;

    const int id   = blockIdx.x;          // 1024 blocks
    const int b    = id & 7;              // batch -> XCD
    const int rest = id >> 3;
    const int ys   = rest & 31;           // y-strip (consecutive on same XCD)
    const int xc   = rest >> 5;           // x quarter (0..3)
    const int x  = xc * 256 + t;          // 1 column per thread
    const int y0 = ys * STRIP;
    const long long ib = (long long)b * IMH * IMW;

    double vx = 0.0, vy = 0.0;            // {h1,h2} running vertical sums (f64 accum)
    #pragma unroll 8
    for (int j = -HALF; j <= HALF; j++) {
        int ry = refl(y0 + j, IMH);
        float2 h = hp[ib + (long long)ry * IMW + x];
        vx += (double)h.x; vy += (double)h.y;
    }

    #pragma unroll 8
    for (int y = y0; y < y0 + STRIP; y++) {
        long long pix = ib + (long long)y * IMW + x;
        double g = (double)gray[pix];

        double m  = vx * INV_AREA;
        double va = fmax(vy * INV_AREA - m * m, 0.0);
        double A  = g - 0.8 * m;
        int o = (A > 0.0) && (A * A * r2 > 0.04 * m * m * va);
        out[pix] = o ? 1.0f : 0.0f;

        int ra = refl(y + HALF + 1, IMH);
        int rs = refl(y - HALF, IMH);
        float2 ha = hp[ib + (long long)ra * IMW + x];
        float2 hs = hp[ib + (long long)rs * IMW + x];
        vx += (double)ha.x - (double)hs.x;
        vy += (double)ha.y - (double)hs.y;
    }
}

extern "C" void kernel_launch(void* const* d_in, const int* in_sizes, int n_in,
                              void* d_out, int out_size, void* d_ws, size_t ws_size,
                              hipStream_t stream) {
    const float* in = (const float*)d_in[0];
    float* out = (float*)d_out;

    unsigned long long* cells = (unsigned long long*)d_ws;      // 2*64 u64
    float2* hp = (float2*)((char*)d_ws + 4096);                 // 67 MB interleaved {h1,h2}
    float* gray = (float*)((char*)d_ws + 4096
                           + (size_t)NB * IMH * IMW * sizeof(float2)); // 33.5 MB staged gray

    hipLaunchKernelGGL(k0_init, dim3(1), dim3(NCELL), 0, stream, cells);
    hipLaunchKernelGGL(k1_rowpass, dim3(NB * IMH), dim3(256), 0, stream,
                       in, hp, gray, cells);
    hipLaunchKernelGGL(k2_colpass, dim3((IMW / 256) * (IMH / STRIP) * NB), dim3(256), 0, stream,
                       gray, hp, cells, out);
}